// Round 12
// baseline (198.508 us; speedup 1.0000x reference)
//
#include <hip/hip_runtime.h>
#include <cstdint>
#include <cstddef>

#define BN 4
#define CC 27
#define HH 160
#define WW 160
#define HWp (HH*WW)        // 25600
#define NPIX (BN*HWp)      // 102400
#define DD 768
#define KK 24
#define NT 400             // 64-px tiles per image
#define NTS 20             // tiles per gemm block: K = 1280 px
#define NSP 20             // splits: NT/NTS
#define GEMMB (BN*6*NSP)   // 480 gemm blocks
#define TAILB (NPIX/256)   // 400 tail blocks

// ---- workspace float offsets ----
#define OFF_ACC 0                        // 32 scalars
#define OFF_S1 32                        // B*K*C = 2592
#define OFF_S2 (OFF_S1+2592)
#define OFF_CNT (OFF_S2+2592)            // 96
#define ZERO_N (OFF_CNT+96)              // 5312 floats zeroed each call
#define OFF_NSQ8 ZERO_N                  // 8*NPIX partials (no zero needed)
#define OFF_LAB (OFF_NSQ8 + 8*NPIX)      // uint8 labels, NPIX bytes
#define OFF_CE (OFF_LAB + NPIX/4)        // NPIX fp32 per-pixel CE
#define OFF_PROBS (OFF_CE + NPIX)        // bf16 probs: BN*CC*HWp ushorts
#define OFF_PP (OFF_PROBS + BN*CC*HWp/2) // NSP*BN*CC*DD fp32 partials (P)
#define OFF_QP (OFF_PP + NSP*BN*CC*DD)
#define OFF_FBF (OFF_QP + NSP*BN*CC*DD)  // fp8 feats TILED (b,dt6,T)[128][64] chunk-perm
#define OFF_WBF (OFF_FBF + (size_t)BN*6*NT*8192/4)  // fp8 W TILED (b,T)[64][64] chunk-perm

typedef __attribute__((ext_vector_type(4))) float f32x4;
typedef __attribute__((ext_vector_type(2))) long longx2;

// within-row byte position for pixel-chunk c (c = n>>3, 8 px per chunk):
// pos = (c&3)*16 + (c>>2)*8  -> one dwordx4 at g*16 yields both K-step frags.
__device__ __forceinline__ int chunkpos(int c) { return (c & 3) * 16 + (c >> 2) * 8; }

__device__ __forceinline__ float wave_sum(float v) {
#pragma unroll
  for (int o = 32; o > 0; o >>= 1) v += __shfl_down(v, o, 64);
  return v;
}

__device__ __forceinline__ unsigned char f2fp8(float x) {
  return (unsigned char)(__builtin_amdgcn_cvt_pk_fp8_f32(x, x, 0, false) & 0xff);
}
__device__ __forceinline__ unsigned short f2bf(float x) {
  unsigned u = __builtin_bit_cast(unsigned, x);
  unsigned r = u + 0x7FFFu + ((u >> 16) & 1u);
  return (unsigned short)(r >> 16);
}
__device__ __forceinline__ float bf2f(unsigned short u) {
  unsigned v = ((unsigned)u) << 16;
  return __builtin_bit_cast(float, v);
}

// k_big: [0,400) fconv: fp32 feats -> fp8 tiled (chunk-perm) + nsq8 slab partials
//        [400,800) mainA: cause argmax + softmax + probs(bf16) + W-pt rows(fp8)
//                      + per-px ce + ent + depth-grad mean
__global__ void __launch_bounds__(256) k_big(const float* __restrict__ feats,
        const float* __restrict__ logits, const float* __restrict__ cause,
        const float* __restrict__ depth,
        unsigned char* __restrict__ fbf, float* __restrict__ nsq8,
        unsigned char* __restrict__ lab, float* __restrict__ ce_arr,
        unsigned short* __restrict__ probs, unsigned char* __restrict__ wbf,
        float* __restrict__ acc) {
  int t = threadIdx.x;
  if (blockIdx.x < 400) {
    int fcid = blockIdx.x;
    int slab = fcid % 50;                // 50 slabs of 2048 px (global)
    int y = fcid / 50;                   // 8-way d split, 96 rows each
    int i = slab * 2048 + 8 * t;
    int b = i / HWp, r = i % HWp;
    int T = r >> 6, chunk = (r & 63) >> 3;
    int pos = chunkpos(chunk);
    const float* src0 = feats + ((size_t)b * DD + y * 96) * HWp + r;
    float n[8] = {0,0,0,0,0,0,0,0};
#pragma unroll 4
    for (int d = 0; d < 96; ++d) {
      int dgl = y * 96 + d;
      const float* src = src0 + (size_t)d * HWp;
      float4 v0 = *(const float4*)src;
      float4 v1 = *(const float4*)(src + 4);
      n[0]+=v0.x*v0.x; n[1]+=v0.y*v0.y; n[2]+=v0.z*v0.z; n[3]+=v0.w*v0.w;
      n[4]+=v1.x*v1.x; n[5]+=v1.y*v1.y; n[6]+=v1.z*v1.z; n[7]+=v1.w*v1.w;
      int pk0 = __builtin_amdgcn_cvt_pk_fp8_f32(v0.x, v0.y, 0, false);
      pk0 = __builtin_amdgcn_cvt_pk_fp8_f32(v0.z, v0.w, pk0, true);
      int pk1 = __builtin_amdgcn_cvt_pk_fp8_f32(v1.x, v1.y, 0, false);
      pk1 = __builtin_amdgcn_cvt_pk_fp8_f32(v1.z, v1.w, pk1, true);
      int dt = dgl >> 7, rin = dgl & 127;
      size_t addr = ((size_t)(b * 6 + dt) * NT + T) * 8192 + rin * 64 + pos;
      int2 pk = make_int2(pk0, pk1);
      *(int2*)&fbf[addr] = pk;
    }
    float* nq = nsq8 + (size_t)y * NPIX + i;
    *(float4*)nq = make_float4(n[0], n[1], n[2], n[3]);
    *(float4*)(nq + 4) = make_float4(n[4], n[5], n[6], n[7]);
  } else {
    int i = (blockIdx.x - 400) * 256 + t;
    int b = i / HWp, r = i % HWp, h = r / WW, w = r % WW;
    float x[CC];
    {
      const float* cp = cause + (size_t)b * CC * HWp + r;
      float best = -1e30f; int bi = 0;
#pragma unroll
      for (int c = 0; c < CC; ++c) {
        float v = cp[(size_t)c * HWp];
        if (v > best) { best = v; bi = c; }
      }
      lab[i] = (unsigned char)bi;
      const float* lg = logits + (size_t)b * CC * HWp + r;
      float m = -1e30f;
#pragma unroll
      for (int c = 0; c < CC; ++c) { x[c] = lg[(size_t)c * HWp]; m = fmaxf(m, x[c]); }
      float sx = 0.f, xl = 0.f;
#pragma unroll
      for (int c = 0; c < CC; ++c) { sx += x[c]; if (c == bi) xl = x[c]; }
      float se = 0.f, set = 0.f, u = 0.f;
#pragma unroll
      for (int c = 0; c < CC; ++c) {
        float tc = x[c] - m;
        float e = expf(tc);
        se += e; u += e * tc;
        float e2 = e * e, e4 = e2 * e2;
        set += e4 * e4 * e2;
        x[c] = e;
      }
      float lse = logf(se);
      float inv_se = 1.f / se, inv_set = 1.f / set;
      float ent = lse - u * inv_se;
      unsigned short* pb = probs + (size_t)b * CC * HWp + r;
      int T = r >> 6, j = r & 63;
      int pos = chunkpos(j >> 3) + (j & 7);
      unsigned char* wb = wbf + ((size_t)b * NT + T) * 4096;
#pragma unroll
      for (int c = 0; c < CC; ++c) {
        float e = x[c];
        pb[(size_t)c * HWp] = f2bf(e * inv_se);
        float e2 = e * e, e4 = e2 * e2;
        float ptc = (e4 * e4 * e2) * inv_set;
        wb[c * 64 + pos] = f2fp8(ptc);
      }
      float ce = 0.8f * (m + lse - xl) + 0.2f * (m + lse - sx * (1.f / CC));
      ce_arr[i] = ce;
      const float* dp = depth + b * HWp;
      float d0 = dp[r];
      float gh = (h < HH-1) ? fabsf(dp[r+WW] - d0) : 0.f;
      float gw = (w < WW-1) ? fabsf(dp[r+1] - d0) : 0.f;
      float g = gh + gw;
      __shared__ float red[2];
      if (t < 2) red[t] = 0.f;
      __syncthreads();
      g = wave_sum(g); float es = wave_sum(ent);
      if ((t & 63) == 0) { atomicAdd(&red[0], g); atomicAdd(&red[1], es); }
      __syncthreads();
      if (t == 0) { atomicAdd(&acc[0], red[0]); atomicAdd(&acc[4], red[1]); }
    }
  }
}

// mainB: W rows 32+c = fp8( fp8dec(pt) * invnorm ). 400 blocks x 4 tiles.
__global__ void __launch_bounds__(256) k_mainB(const float* __restrict__ nsq8,
        unsigned char* __restrict__ wbf) {
  int t = threadIdx.x;
  int tt = blockIdx.x * 4 + (t >> 6);    // global tile in [0, BN*NT)
  int j = t & 63;
  int b = tt / NT, T = tt % NT;
  int i = b * HWp + T * 64 + j;
  float ns = 0.f;
#pragma unroll
  for (int y = 0; y < 8; ++y) ns += nsq8[(size_t)y * NPIX + i];
  float invn = 1.f / fmaxf(sqrtf(ns), 1e-12f);
  unsigned char* wb = wbf + ((size_t)b * NT + T) * 4096;
  int pos = chunkpos(j >> 3) + (j & 7);
#pragma unroll
  for (int c = 0; c < CC; ++c) {
    int a1 = c * 64 + pos;
    float f = __builtin_amdgcn_cvt_f32_fp8((int)wb[a1], 0);
    wb[a1 + 32 * 64] = f2fp8(f * invn);
  }
}

// fused co-scheduled kernel:
//   blocks [0,480): register-direct fp8 MFMA GEMM — NO LDS, NO barriers,
//                   3-slot software pipeline (fully unrolled, static regs)
//   blocks [480,880): tail (distill + bpl + align + instance BCE + iu histogram)
__global__ void __launch_bounds__(256) k_gemmtail(const unsigned char* __restrict__ fbf,
        const unsigned char* __restrict__ wbf,
        float* __restrict__ Pp, float* __restrict__ Qp,
        const unsigned short* __restrict__ probs, const float* __restrict__ depth,
        const int* __restrict__ inst, const unsigned char* __restrict__ lab,
        const float* __restrict__ ce_arr, float* __restrict__ acc,
        float* __restrict__ s1g, float* __restrict__ s2g, float* __restrict__ cntg) {
  __shared__ float tsm[4*KK*CC*2 + 4*KK + 8];   // tail-only (~21 KB)
  int t = threadIdx.x;
  if (blockIdx.x < GEMMB) {
    int orig = blockIdx.x;
    int bx = (orig & 7) * 60 + (orig >> 3);   // bijective: 480 = 8*60
    int s  = bx % NSP;
    int dt = (bx / NSP) % 6;
    int b  = bx / (NSP * 6);
    int wave = t >> 6, lane = t & 63;
    int g = lane >> 4, rr = lane & 15;
    f32x4 acc4[2][4] = {};
    // per-lane fragment bases: one dwordx4 = both K-step frags of a 16-row band
    const unsigned char* At = fbf + ((size_t)(b*6+dt)*NT + s*NTS) * 8192
                             + (wave*32 + rr) * 64 + g*16;
    const unsigned char* Wt = wbf + ((size_t)b*NT + s*NTS) * 4096 + rr*64 + g*16;
    longx2 af[3][2], wf[3][4];
#pragma unroll
    for (int p = 0; p < 3; ++p) {
#pragma unroll
      for (int dd = 0; dd < 2; ++dd)
        af[p][dd] = *(const longx2*)(At + (size_t)p*8192 + dd*1024);
#pragma unroll
      for (int ct = 0; ct < 4; ++ct)
        wf[p][ct] = *(const longx2*)(Wt + (size_t)p*4096 + ct*1024);
    }
#pragma unroll
    for (int tc = 0; tc < NTS; ++tc) {
      const int sl = tc % 3;
#pragma unroll
      for (int dd = 0; dd < 2; ++dd)
#pragma unroll
        for (int ct = 0; ct < 4; ++ct) {
          acc4[dd][ct] = __builtin_amdgcn_mfma_f32_16x16x32_fp8_fp8(
              af[sl][dd].x, wf[sl][ct].x, acc4[dd][ct], 0, 0, 0);
          acc4[dd][ct] = __builtin_amdgcn_mfma_f32_16x16x32_fp8_fp8(
              af[sl][dd].y, wf[sl][ct].y, acc4[dd][ct], 0, 0, 0);
        }
      if (tc + 3 < NTS) {
#pragma unroll
        for (int dd = 0; dd < 2; ++dd)
          af[sl][dd] = *(const longx2*)(At + (size_t)(tc+3)*8192 + dd*1024);
#pragma unroll
        for (int ct = 0; ct < 4; ++ct)
          wf[sl][ct] = *(const longx2*)(Wt + (size_t)(tc+3)*4096 + ct*1024);
      }
    }
    // epilogue: C/D layout col=lane&15 (c'), row=(lane>>4)*4+reg (d)
#pragma unroll
    for (int dd = 0; dd < 2; ++dd) {
#pragma unroll
      for (int ct = 0; ct < 4; ++ct) {
        int cp = ct * 16 + rr;
        int d = dt * 128 + wave * 32 + dd * 16 + g * 4;
        f32x4 v = acc4[dd][ct];
        if (cp < CC)
          *(f32x4*)&Pp[(((size_t)s * BN + b) * CC + cp) * DD + d] = v;
        else if (cp >= 32 && cp < 32 + CC)
          *(f32x4*)&Qp[(((size_t)s * BN + b) * CC + (cp - 32)) * DD + d] = v;
      }
    }
  } else {
    float* ls1 = tsm;                          // [4][KK*CC]
    float* ls2 = ls1 + 4*KK*CC;
    float* lc  = ls2 + 4*KK*CC;                // [4][KK]
    float* red = lc + 4*KK;                    // [7]
    int wv = t >> 6;
    for (int idx = t; idx < 4*KK*CC; idx += 256) { ls1[idx] = 0.f; ls2[idx] = 0.f; }
    if (t < 4*KK) lc[t] = 0.f;
    if (t < 7) red[t] = 0.f;
    __syncthreads();
    int i = (blockIdx.x - GEMMB) * 256 + t;
    int b = i / HWp, r = i % HWp, h = r / WW, w = r % WW;
    const unsigned short* P = probs + (size_t)b * CC * HWp + r;
    const int* ip = inst + b * HWp;
    int id = ip[r];
    atomicAdd(&lc[wv*KK + id], 1.f);
    bool hasR = (w < WW-1), hasD = (h < HH-1);
    float sh = 0.f, sv = 0.f, mh = 0.f, mw = 0.f;
#pragma unroll
    for (int c = 0; c < CC; ++c) {
      float p  = bf2f(P[(size_t)c * HWp]);
      atomicAdd(&ls1[(wv*KK + id)*CC + c], p);
      atomicAdd(&ls2[(wv*KK + id)*CC + c], p * p);
      float pr = hasR ? bf2f(P[(size_t)c * HWp + 1])  : p;
      float pd = hasD ? bf2f(P[(size_t)c * HWp + WW]) : p;
      float dr = pr - p, dd = pd - p;
      sh += dr * dr; sv += dd * dd;
      mw = fmaxf(mw, fabsf(dr)); mh = fmaxf(mh, fabsf(dd));
    }
    const float* dp = depth + b * HWp;
    float d0 = dp[r];
    float aH = 0.f, aV = 0.f, bh = 0.f, bw = 0.f;
    float gh = 0.f, gw = 0.f;
    if (hasR) {
      float ddh = dp[r+1] - d0;
      gw = fabsf(ddh);
      aH = expf(-(ddh*ddh) * 200.f) * sh;
      float y = (ip[r+1] != ip[r]) ? 1.f : 0.f;
      float xx = fminf(fmaxf(mw, 1e-6f), 1.f - 1e-6f);
      bw = -(y * logf(xx) + (1.f - y) * log1pf(-xx));
    }
    if (hasD) {
      float ddv = dp[r+WW] - d0;
      gh = fabsf(ddv);
      aV = expf(-(ddv*ddv) * 200.f) * sv;
      float y = (ip[r+WW] != ip[r]) ? 1.f : 0.f;
      float xx = fminf(fmaxf(mh, 1e-6f), 1.f - 1e-6f);
      bh = -(y * logf(xx) + (1.f - y) * log1pf(-xx));
    }
    float ce = ce_arr[i];
    int l = lab[i];
    float ptf = expf(-ce);
    float wgt = (1.f - ptf) * (1.f - ptf);
    if (l >= 11 && l <= 18) wgt *= 2.f;
    float gmean = acc[0] * (1.f / NPIX);
    float gnorm = (gh + gw) / (gmean + 1e-6f);
    wgt *= 1.f + 0.1f * fminf(gnorm, 3.f);
    const unsigned char* lb = lab + b * HWp;
    int lL = lb[h*WW + (w>0 ? w-1 : w)];
    int lR = lb[h*WW + (w<WW-1 ? w+1 : w)];
    int lU = lb[(h>0 ? h-1 : h)*WW + w];
    int lD = lb[(h<HH-1 ? h+1 : h)*WW + w];
    float bnd = ((l != lL) | (l != lR) | (l != lU) | (l != lD)) ? 1.f : 0.f;
    float c_dist = ce * wgt, c_bnum = ce * bnd, c_bcnt = bnd;
    __syncthreads();
    aH = wave_sum(aH); aV = wave_sum(aV); bh = wave_sum(bh); bw = wave_sum(bw);
    c_dist = wave_sum(c_dist); c_bnum = wave_sum(c_bnum); c_bcnt = wave_sum(c_bcnt);
    if ((t & 63) == 0) {
      atomicAdd(&red[0], aH); atomicAdd(&red[1], aV);
      atomicAdd(&red[2], bh); atomicAdd(&red[3], bw);
      atomicAdd(&red[4], c_dist); atomicAdd(&red[5], c_bnum); atomicAdd(&red[6], c_bcnt);
    }
    __syncthreads();
    if (t == 0) {
      atomicAdd(&acc[5], red[0]); atomicAdd(&acc[6], red[1]);
      atomicAdd(&acc[7], red[2]); atomicAdd(&acc[8], red[3]);
      atomicAdd(&acc[1], red[4]); atomicAdd(&acc[2], red[5]); atomicAdd(&acc[3], red[6]);
    }
    for (int idx = t; idx < KK*CC; idx += 256) {
      atomicAdd(&s1g[b*KK*CC + idx], ls1[idx]+ls1[KK*CC+idx]+ls1[2*KK*CC+idx]+ls1[3*KK*CC+idx]);
      atomicAdd(&s2g[b*KK*CC + idx], ls2[idx]+ls2[KK*CC+idx]+ls2[2*KK*CC+idx]+ls2[3*KK*CC+idx]);
    }
    if (t < KK) atomicAdd(&cntg[b*KK + t], lc[t]+lc[KK+t]+lc[2*KK+t]+lc[3*KK+t]);
  }
}

__global__ void k_pfinal(const float* __restrict__ Pp, const float* __restrict__ Qp,
                         float* __restrict__ acc) {
  int bc = blockIdx.x;   // b*CC + c
  int b = bc / CC, c = bc % CC;
  float dot = 0.f, nsq = 0.f;
  for (int d = threadIdx.x; d < DD; d += 256) {
    float p = 0.f, q = 0.f;
#pragma unroll
    for (int s = 0; s < NSP; ++s) {
      size_t off = (((size_t)s * BN + b) * CC + c) * DD + d;
      p += Pp[off]; q += Qp[off];
    }
    dot += p * q; nsq += p * p;
  }
  __shared__ float red[2];
  if (threadIdx.x < 2) red[threadIdx.x] = 0.f;
  __syncthreads();
  dot = wave_sum(dot); nsq = wave_sum(nsq);
  if ((threadIdx.x & 63) == 0) { atomicAdd(&red[0], dot); atomicAdd(&red[1], nsq); }
  __syncthreads();
  if (threadIdx.x == 0) atomicAdd(&acc[9], red[0] / fmaxf(sqrtf(red[1]), 1e-12f));
}

__global__ void k_final(const float* __restrict__ s1g, const float* __restrict__ s2g,
                        const float* __restrict__ cntg, const float* __restrict__ acc,
                        float* __restrict__ out) {
  int t = threadIdx.x;
  float vsum = 0.f, vcnt = 0.f;
  if (t < BN*KK) {
    int k = t % KK;
    float count = cntg[t];
    float nc = fmaxf(count, 1.f);
    float var = 0.f;
#pragma unroll
    for (int c = 0; c < CC; ++c) {
      float m1 = s1g[t*CC + c] / nc;
      var += s2g[t*CC + c] / nc - m1 * m1;
    }
    var *= (1.f / CC);
    if (k > 0 && count >= 25.f) { vsum = var; vcnt = 1.f; }
  }
  __shared__ float red[2];
  if (t < 2) red[t] = 0.f;
  __syncthreads();
  vsum = wave_sum(vsum); vcnt = wave_sum(vcnt);
  if ((t & 63) == 0) { atomicAdd(&red[0], vsum); atomicAdd(&red[1], vcnt); }
  __syncthreads();
  if (t == 0) {
    float l_distill = acc[1] * (1.f / NPIX);
    float bcnt = acc[3];
    float l_bpl = (bcnt > 0.f) ? acc[2] / fmaxf(bcnt, 1.f) : 0.f;
    float l_align = acc[5] * (1.f / (BN*HH*(WW-1))) + acc[6] * (1.f / (BN*(HH-1)*WW));
    float l_ent = acc[4] * (1.f / NPIX);
    float l_ib = 0.5f * (acc[7] * (1.f / (BN*(HH-1)*WW)) + acc[8] * (1.f / (BN*HH*(WW-1))));
    float l_proto = -acc[9] * (1.f / NPIX);
    float l_iu = red[0] / fmaxf(red[1], 1.f);
    out[0] = 1.0f*l_distill + 0.5f*l_bpl + 5.0f*l_align + 0.5f*l_proto +
             0.3f*l_ent + 0.5f*l_iu + 0.5f*l_ib;
  }
}

extern "C" void kernel_launch(void* const* d_in, const int* in_sizes, int n_in,
                              void* d_out, int out_size, void* d_ws, size_t ws_size,
                              hipStream_t stream) {
  (void)in_sizes; (void)n_in; (void)out_size; (void)ws_size;
  const float* logits = (const float*)d_in[0];
  const float* cause  = (const float*)d_in[1];
  const float* feats  = (const float*)d_in[2];
  const float* depth  = (const float*)d_in[3];
  const int*   inst   = (const int*)d_in[4];
  float* ws = (float*)d_ws;
  float* acc = ws + OFF_ACC;
  float* s1  = ws + OFF_S1;
  float* s2  = ws + OFF_S2;
  float* cnt = ws + OFF_CNT;
  float* nsq8 = ws + OFF_NSQ8;
  float* ce  = ws + OFF_CE;
  float* Pp  = ws + OFF_PP;
  float* Qp  = ws + OFF_QP;
  unsigned char* lab = (unsigned char*)(ws + OFF_LAB);
  unsigned short* probs = (unsigned short*)(ws + OFF_PROBS);
  unsigned char* fbf = (unsigned char*)(ws + OFF_FBF);
  unsigned char* wbf = (unsigned char*)(ws + OFF_WBF);
  float* out = (float*)d_out;

  hipMemsetAsync(ws, 0, (size_t)ZERO_N * 4, stream);
  k_big<<<800, 256, 0, stream>>>(feats, logits, cause, depth, fbf, nsq8, lab, ce,
                                 probs, wbf, acc);
  k_mainB<<<400, 256, 0, stream>>>(nsq8, wbf);
  k_gemmtail<<<GEMMB + TAILB, 256, 0, stream>>>(fbf, wbf, Pp, Qp, probs, depth, inst,
                                                lab, ce, acc, s1, s2, cnt);
  k_pfinal<<<BN * CC, 256, 0, stream>>>(Pp, Qp, acc);
  k_final<<<1, 256, 0, stream>>>(s1, s2, cnt, acc, out);
}

// Round 14
// 193.345 us; speedup vs baseline: 1.0267x; 1.0267x over previous
//
#include <hip/hip_runtime.h>
#include <cstdint>
#include <cstddef>

#define BN 4
#define CC 27
#define HH 160
#define WW 160
#define HWp (HH*WW)        // 25600
#define NPIX (BN*HWp)      // 102400
#define DD 768
#define KK 24
#define NT 400             // 64-px tiles per image
#define NTS 20             // tiles per gemm block: K = 1280 px
#define NSP 20             // splits: NT/NTS
#define NPH (NTS/2)        // 10 two-chunk phases
#define GEMMB (BN*6*NSP)   // 480 gemm blocks
#define TAILB (NPIX/256)   // 400 tail blocks

// ---- workspace float offsets ----
#define OFF_ACC 0                        // 32 scalars
#define OFF_S1 32                        // B*K*C = 2592
#define OFF_S2 (OFF_S1+2592)
#define OFF_CNT (OFF_S2+2592)            // 96
#define ZERO_N (OFF_CNT+96)              // 5312 floats zeroed each call
#define OFF_NSQ8 ZERO_N                  // 8*NPIX partials (no zero needed)
#define OFF_LAB (OFF_NSQ8 + 8*NPIX)      // uint8 labels, NPIX bytes
#define OFF_CE (OFF_LAB + NPIX/4)        // NPIX fp32 per-pixel CE
#define OFF_PROBS (OFF_CE + NPIX)        // bf16 probs: BN*CC*HWp ushorts
#define OFF_PP (OFF_PROBS + BN*CC*HWp/2) // NSP*BN*CC*DD fp32 partials (P)
#define OFF_QP (OFF_PP + NSP*BN*CC*DD)
#define OFF_FBF (OFF_QP + NSP*BN*CC*DD)  // fp8 feats TILED (b,dt6,T)[128][64] swizzled
#define OFF_WBF (OFF_FBF + (size_t)BN*6*NT*8192/4)  // fp8 W TILED (b,T)[64][64] swizzled

typedef __attribute__((ext_vector_type(4))) float f32x4;

__device__ __forceinline__ float wave_sum(float v) {
#pragma unroll
  for (int o = 32; o > 0; o >>= 1) v += __shfl_down(v, o, 64);
  return v;
}

__device__ __forceinline__ unsigned char f2fp8(float x) {
  return (unsigned char)(__builtin_amdgcn_cvt_pk_fp8_f32(x, x, 0, false) & 0xff);
}
__device__ __forceinline__ unsigned short f2bf(float x) {
  unsigned u = __builtin_bit_cast(unsigned, x);
  unsigned r = u + 0x7FFFu + ((u >> 16) & 1u);
  return (unsigned short)(r >> 16);
}
__device__ __forceinline__ float bf2f(unsigned short u) {
  unsigned v = ((unsigned)u) << 16;
  return __builtin_bit_cast(float, v);
}

__global__ void k_zero(float* __restrict__ w, int n) {
  int i = blockIdx.x * 256 + threadIdx.x;
  if (i < n) w[i] = 0.f;
}

// k_big: [0,400) fconv: fp32 feats -> fp8 tiled/swizzled (8 px/thread)
//                      + nsq8 slab partials
//        [400,800) mainA: cause argmax + softmax + probs(bf16) + W-pt rows(fp8)
//                      + per-px ce + ent + depth-grad mean  (independent of feats)
__global__ void __launch_bounds__(256) k_big(const float* __restrict__ feats,
        const float* __restrict__ logits, const float* __restrict__ cause,
        const float* __restrict__ depth,
        unsigned char* __restrict__ fbf, float* __restrict__ nsq8,
        unsigned char* __restrict__ lab, float* __restrict__ ce_arr,
        unsigned short* __restrict__ probs, unsigned char* __restrict__ wbf,
        float* __restrict__ acc) {
  int t = threadIdx.x;
  if (blockIdx.x < 400) {
    int fcid = blockIdx.x;
    int slab = fcid % 50;                // 50 slabs of 2048 px (global)
    int y = fcid / 50;                   // 8-way d split, 96 rows each
    int i = slab * 2048 + 8 * t;
    int b = i / HWp, r = i % HWp;
    int T = r >> 6, chunk = (r & 63) >> 3;
    const float* src0 = feats + ((size_t)b * DD + y * 96) * HWp + r;
    float n[8] = {0,0,0,0,0,0,0,0};
#pragma unroll 4
    for (int d = 0; d < 96; ++d) {
      int dgl = y * 96 + d;
      const float* src = src0 + (size_t)d * HWp;
      float4 v0 = *(const float4*)src;
      float4 v1 = *(const float4*)(src + 4);
      n[0]+=v0.x*v0.x; n[1]+=v0.y*v0.y; n[2]+=v0.z*v0.z; n[3]+=v0.w*v0.w;
      n[4]+=v1.x*v1.x; n[5]+=v1.y*v1.y; n[6]+=v1.z*v1.z; n[7]+=v1.w*v1.w;
      int pk0 = __builtin_amdgcn_cvt_pk_fp8_f32(v0.x, v0.y, 0, false);
      pk0 = __builtin_amdgcn_cvt_pk_fp8_f32(v0.z, v0.w, pk0, true);
      int pk1 = __builtin_amdgcn_cvt_pk_fp8_f32(v1.x, v1.y, 0, false);
      pk1 = __builtin_amdgcn_cvt_pk_fp8_f32(v1.z, v1.w, pk1, true);
      int dt = dgl >> 7, rin = dgl & 127;
      size_t addr = ((size_t)(b * 6 + dt) * NT + T) * 8192 + rin * 64
                  + ((chunk ^ (rin & 7)) * 8);
      int2 pk = make_int2(pk0, pk1);
      *(int2*)&fbf[addr] = pk;
    }
    float* nq = nsq8 + (size_t)y * NPIX + i;
    *(float4*)nq = make_float4(n[0], n[1], n[2], n[3]);
    *(float4*)(nq + 4) = make_float4(n[4], n[5], n[6], n[7]);
  } else {
    int i = (blockIdx.x - 400) * 256 + t;
    int b = i / HWp, r = i % HWp, h = r / WW, w = r % WW;
    float x[CC];
    {
      const float* cp = cause + (size_t)b * CC * HWp + r;
      float best = -1e30f; int bi = 0;
#pragma unroll
      for (int c = 0; c < CC; ++c) {
        float v = cp[(size_t)c * HWp];
        if (v > best) { best = v; bi = c; }
      }
      lab[i] = (unsigned char)bi;
      const float* lg = logits + (size_t)b * CC * HWp + r;
      float m = -1e30f;
#pragma unroll
      for (int c = 0; c < CC; ++c) { x[c] = lg[(size_t)c * HWp]; m = fmaxf(m, x[c]); }
      float sx = 0.f, xl = 0.f;
#pragma unroll
      for (int c = 0; c < CC; ++c) { sx += x[c]; if (c == bi) xl = x[c]; }
      float se = 0.f, set = 0.f, u = 0.f;
#pragma unroll
      for (int c = 0; c < CC; ++c) {
        float tc = x[c] - m;
        float e = expf(tc);
        se += e; u += e * tc;
        float e2 = e * e, e4 = e2 * e2;
        set += e4 * e4 * e2;
        x[c] = e;
      }
      float lse = logf(se);
      float inv_se = 1.f / se, inv_set = 1.f / set;
      float ent = lse - u * inv_se;
      unsigned short* pb = probs + (size_t)b * CC * HWp + r;
      int T = r >> 6, j = r & 63;
      unsigned char* wb = wbf + ((size_t)b * NT + T) * 4096;
#pragma unroll
      for (int c = 0; c < CC; ++c) {
        float e = x[c];
        pb[(size_t)c * HWp] = f2bf(e * inv_se);
        float e2 = e * e, e4 = e2 * e2;
        float ptc = (e4 * e4 * e2) * inv_set;
        wb[c * 64 + (((j >> 3) ^ (c & 7)) * 8) + (j & 7)] = f2fp8(ptc);
      }
      float ce = 0.8f * (m + lse - xl) + 0.2f * (m + lse - sx * (1.f / CC));
      ce_arr[i] = ce;
      const float* dp = depth + b * HWp;
      float d0 = dp[r];
      float gh = (h < HH-1) ? fabsf(dp[r+WW] - d0) : 0.f;
      float gw = (w < WW-1) ? fabsf(dp[r+1] - d0) : 0.f;
      float g = gh + gw;
      __shared__ float red[2];
      if (t < 2) red[t] = 0.f;
      __syncthreads();
      g = wave_sum(g); float es = wave_sum(ent);
      if ((t & 63) == 0) { atomicAdd(&red[0], g); atomicAdd(&red[1], es); }
      __syncthreads();
      if (t == 0) { atomicAdd(&acc[0], red[0]); atomicAdd(&acc[4], red[1]); }
    }
  }
}

// mainB: W rows 32+c = fp8( fp8dec(pt) * invnorm ). 400 blocks x 4 tiles.
__global__ void __launch_bounds__(256) k_mainB(const float* __restrict__ nsq8,
        unsigned char* __restrict__ wbf) {
  int t = threadIdx.x;
  int tt = blockIdx.x * 4 + (t >> 6);    // global tile in [0, BN*NT)
  int j = t & 63;
  int b = tt / NT, T = tt % NT;
  int i = b * HWp + T * 64 + j;
  float ns = 0.f;
#pragma unroll
  for (int y = 0; y < 8; ++y) ns += nsq8[(size_t)y * NPIX + i];
  float invn = 1.f / fmaxf(sqrtf(ns), 1e-12f);
  unsigned char* wb = wbf + ((size_t)b * NT + T) * 4096;
#pragma unroll
  for (int c = 0; c < CC; ++c) {
    int a1 = c * 64 + ((((j >> 3) ^ (c & 7))) * 8) + (j & 7);
    float f = __builtin_amdgcn_cvt_f32_fp8((int)wb[a1], 0);
    wb[a1 + 32 * 64] = f2fp8(f * invn);
  }
}

// fused co-scheduled kernel:
//   blocks [0,480): fp8 MFMA GEMM, 72KB LDS, triple-buffered DMA (vmcnt(12)),
//                   two-chunk barrier phases, atomic-free partial epilogue
//   blocks [480,880): tail (distill + bpl + align + instance BCE + iu histogram)
__global__ void __launch_bounds__(256) k_gemmtail(const unsigned char* __restrict__ fbf,
        const unsigned char* __restrict__ wbf,
        float* __restrict__ Pp, float* __restrict__ Qp,
        const unsigned short* __restrict__ probs, const float* __restrict__ depth,
        const int* __restrict__ inst, const unsigned char* __restrict__ lab,
        const float* __restrict__ ce_arr, float* __restrict__ acc,
        float* __restrict__ s1g, float* __restrict__ s2g, float* __restrict__ cntg) {
  __shared__ __align__(16) unsigned char smem[73728];
  int t = threadIdx.x;
  if (blockIdx.x < GEMMB) {
    unsigned char (*As)[2][8192] = (unsigned char (*)[2][8192])smem;
    unsigned char (*Ws)[2][4096] = (unsigned char (*)[2][4096])(smem + 49152);
    int orig = blockIdx.x;
    int bx = (orig & 7) * 60 + (orig >> 3);   // bijective: 480 = 8*60
    int s  = bx % NSP;
    int dt = (bx / NSP) % 6;
    int b  = bx / (NSP * 6);
    int wave = t >> 6, lane = t & 63;
    int g = lane >> 4, rr = lane & 15;
    f32x4 acc4[2][4] = {};
    const unsigned char* Abase = fbf + ((size_t)(b*6+dt)*NT + s*NTS) * 8192;
    const unsigned char* Wbase = wbf + ((size_t)b*NT + s*NTS) * 4096;

#define STAGE2(ph, bufi) do { \
    _Pragma("unroll") \
    for (int c2_ = 0; c2_ < 2; ++c2_) { \
      const unsigned char* as_ = Abase + (size_t)((ph)*2 + c2_) * 8192; \
      const unsigned char* ws_ = Wbase + (size_t)((ph)*2 + c2_) * 4096; \
      _Pragma("unroll") \
      for (int i_ = 0; i_ < 2; ++i_) { \
        int off_ = wave*2048 + i_*1024; \
        __builtin_amdgcn_global_load_lds( \
          (const __attribute__((address_space(1))) void*)(as_ + off_ + lane*16), \
          (__attribute__((address_space(3))) void*)&As[bufi][c2_][off_], 16, 0, 0); \
      } \
      { \
        int off_ = wave*1024; \
        __builtin_amdgcn_global_load_lds( \
          (const __attribute__((address_space(1))) void*)(ws_ + off_ + lane*16), \
          (__attribute__((address_space(3))) void*)&Ws[bufi][c2_][off_], 16, 0, 0); \
      } \
    } \
  } while (0)

    STAGE2(0, 0);
    STAGE2(1, 1);
    int cur = 0;
    for (int ph = 0; ph < NPH; ++ph) {
      if (ph + 2 < NPH) {
        STAGE2(ph + 2, (cur + 2) % 3);
        asm volatile("s_waitcnt vmcnt(12)" ::: "memory");
      } else if (ph + 1 < NPH) {
        asm volatile("s_waitcnt vmcnt(6)" ::: "memory");
      } else {
        asm volatile("s_waitcnt vmcnt(0)" ::: "memory");
      }
      __builtin_amdgcn_s_barrier();
      __builtin_amdgcn_sched_barrier(0);
#pragma unroll
      for (int c2 = 0; c2 < 2; ++c2) {
#pragma unroll
        for (int ks = 0; ks < 2; ++ks) {
          long a[2]; long wf[4];
#pragma unroll
          for (int dd = 0; dd < 2; ++dd) {
            int row = (wave*2 + dd)*16 + rr;
            int ck = (ks*4 + g) ^ (row & 7);
            a[dd] = *(const long*)&As[cur][c2][row*64 + ck*8];
          }
#pragma unroll
          for (int ct = 0; ct < 4; ++ct) {
            int row = ct*16 + rr;
            int ck = (ks*4 + g) ^ (row & 7);
            wf[ct] = *(const long*)&Ws[cur][c2][row*64 + ck*8];
          }
#pragma unroll
          for (int dd = 0; dd < 2; ++dd)
#pragma unroll
            for (int ct = 0; ct < 4; ++ct)
              acc4[dd][ct] = __builtin_amdgcn_mfma_f32_16x16x32_fp8_fp8(a[dd], wf[ct], acc4[dd][ct], 0, 0, 0);
        }
      }
      __builtin_amdgcn_sched_barrier(0);
      __builtin_amdgcn_s_barrier();
      cur = (cur + 1) % 3;
    }
#undef STAGE2
#pragma unroll
    for (int dd = 0; dd < 2; ++dd) {
#pragma unroll
      for (int ct = 0; ct < 4; ++ct) {
        int cp = ct * 16 + rr;
        int d = dt * 128 + (wave * 2 + dd) * 16 + g * 4;
        f32x4 v = acc4[dd][ct];
        if (cp < CC)
          *(f32x4*)&Pp[(((size_t)s * BN + b) * CC + cp) * DD + d] = v;
        else if (cp >= 32 && cp < 32 + CC)
          *(f32x4*)&Qp[(((size_t)s * BN + b) * CC + (cp - 32)) * DD + d] = v;
      }
    }
  } else {
    float* ls1 = (float*)smem;                 // [4][KK*CC]
    float* ls2 = ls1 + 4*KK*CC;
    float* lc  = ls2 + 4*KK*CC;                // [4][KK]
    float* red = lc + 4*KK;                    // [7]
    int wv = t >> 6;
    for (int idx = t; idx < 4*KK*CC; idx += 256) { ls1[idx] = 0.f; ls2[idx] = 0.f; }
    if (t < 4*KK) lc[t] = 0.f;
    if (t < 7) red[t] = 0.f;
    __syncthreads();
    int i = (blockIdx.x - GEMMB) * 256 + t;
    int b = i / HWp, r = i % HWp, h = r / WW, w = r % WW;
    const unsigned short* P = probs + (size_t)b * CC * HWp + r;
    const int* ip = inst + b * HWp;
    int id = ip[r];
    atomicAdd(&lc[wv*KK + id], 1.f);
    bool hasR = (w < WW-1), hasD = (h < HH-1);
    float sh = 0.f, sv = 0.f, mh = 0.f, mw = 0.f;
#pragma unroll
    for (int c = 0; c < CC; ++c) {
      float p  = bf2f(P[(size_t)c * HWp]);
      atomicAdd(&ls1[(wv*KK + id)*CC + c], p);
      atomicAdd(&ls2[(wv*KK + id)*CC + c], p * p);
      float pr = hasR ? bf2f(P[(size_t)c * HWp + 1])  : p;
      float pd = hasD ? bf2f(P[(size_t)c * HWp + WW]) : p;
      float dr = pr - p, dd = pd - p;
      sh += dr * dr; sv += dd * dd;
      mw = fmaxf(mw, fabsf(dr)); mh = fmaxf(mh, fabsf(dd));
    }
    const float* dp = depth + b * HWp;
    float d0 = dp[r];
    float aH = 0.f, aV = 0.f, bh = 0.f, bw = 0.f;
    float gh = 0.f, gw = 0.f;
    if (hasR) {
      float ddh = dp[r+1] - d0;
      gw = fabsf(ddh);
      aH = expf(-(ddh*ddh) * 200.f) * sh;
      float y = (ip[r+1] != ip[r]) ? 1.f : 0.f;
      float xx = fminf(fmaxf(mw, 1e-6f), 1.f - 1e-6f);
      bw = -(y * logf(xx) + (1.f - y) * log1pf(-xx));
    }
    if (hasD) {
      float ddv = dp[r+WW] - d0;
      gh = fabsf(ddv);
      aV = expf(-(ddv*ddv) * 200.f) * sv;
      float y = (ip[r+WW] != ip[r]) ? 1.f : 0.f;
      float xx = fminf(fmaxf(mh, 1e-6f), 1.f - 1e-6f);
      bh = -(y * logf(xx) + (1.f - y) * log1pf(-xx));
    }
    float ce = ce_arr[i];
    int l = lab[i];
    float ptf = expf(-ce);
    float wgt = (1.f - ptf) * (1.f - ptf);
    if (l >= 11 && l <= 18) wgt *= 2.f;
    float gmean = acc[0] * (1.f / NPIX);
    float gnorm = (gh + gw) / (gmean + 1e-6f);
    wgt *= 1.f + 0.1f * fminf(gnorm, 3.f);
    const unsigned char* lb = lab + b * HWp;
    int lL = lb[h*WW + (w>0 ? w-1 : w)];
    int lR = lb[h*WW + (w<WW-1 ? w+1 : w)];
    int lU = lb[(h>0 ? h-1 : h)*WW + w];
    int lD = lb[(h<HH-1 ? h+1 : h)*WW + w];
    float bnd = ((l != lL) | (l != lR) | (l != lU) | (l != lD)) ? 1.f : 0.f;
    float c_dist = ce * wgt, c_bnum = ce * bnd, c_bcnt = bnd;
    __syncthreads();
    aH = wave_sum(aH); aV = wave_sum(aV); bh = wave_sum(bh); bw = wave_sum(bw);
    c_dist = wave_sum(c_dist); c_bnum = wave_sum(c_bnum); c_bcnt = wave_sum(c_bcnt);
    if ((t & 63) == 0) {
      atomicAdd(&red[0], aH); atomicAdd(&red[1], aV);
      atomicAdd(&red[2], bh); atomicAdd(&red[3], bw);
      atomicAdd(&red[4], c_dist); atomicAdd(&red[5], c_bnum); atomicAdd(&red[6], c_bcnt);
    }
    __syncthreads();
    if (t == 0) {
      atomicAdd(&acc[5], red[0]); atomicAdd(&acc[6], red[1]);
      atomicAdd(&acc[7], red[2]); atomicAdd(&acc[8], red[3]);
      atomicAdd(&acc[1], red[4]); atomicAdd(&acc[2], red[5]); atomicAdd(&acc[3], red[6]);
    }
    for (int idx = t; idx < KK*CC; idx += 256) {
      atomicAdd(&s1g[b*KK*CC + idx], ls1[idx]+ls1[KK*CC+idx]+ls1[2*KK*CC+idx]+ls1[3*KK*CC+idx]);
      atomicAdd(&s2g[b*KK*CC + idx], ls2[idx]+ls2[KK*CC+idx]+ls2[2*KK*CC+idx]+ls2[3*KK*CC+idx]);
    }
    if (t < KK) atomicAdd(&cntg[b*KK + t], lc[t]+lc[KK+t]+lc[2*KK+t]+lc[3*KK+t]);
  }
}

__global__ void k_pfinal(const float* __restrict__ Pp, const float* __restrict__ Qp,
                         float* __restrict__ acc) {
  int bc = blockIdx.x;   // b*CC + c
  int b = bc / CC, c = bc % CC;
  float dot = 0.f, nsq = 0.f;
  for (int d = threadIdx.x; d < DD; d += 256) {
    float p = 0.f, q = 0.f;
#pragma unroll
    for (int s = 0; s < NSP; ++s) {
      size_t off = (((size_t)s * BN + b) * CC + c) * DD + d;
      p += Pp[off]; q += Qp[off];
    }
    dot += p * q; nsq += p * p;
  }
  __shared__ float red[2];
  if (threadIdx.x < 2) red[threadIdx.x] = 0.f;
  __syncthreads();
  dot = wave_sum(dot); nsq = wave_sum(nsq);
  if ((threadIdx.x & 63) == 0) { atomicAdd(&red[0], dot); atomicAdd(&red[1], nsq); }
  __syncthreads();
  if (threadIdx.x == 0) atomicAdd(&acc[9], red[0] / fmaxf(sqrtf(red[1]), 1e-12f));
}

__global__ void k_final(const float* __restrict__ s1g, const float* __restrict__ s2g,
                        const float* __restrict__ cntg, const float* __restrict__ acc,
                        float* __restrict__ out) {
  int t = threadIdx.x;
  float vsum = 0.f, vcnt = 0.f;
  if (t < BN*KK) {
    int k = t % KK;
    float count = cntg[t];
    float nc = fmaxf(count, 1.f);
    float var = 0.f;
#pragma unroll
    for (int c = 0; c < CC; ++c) {
      float m1 = s1g[t*CC + c] / nc;
      var += s2g[t*CC + c] / nc - m1 * m1;
    }
    var *= (1.f / CC);
    if (k > 0 && count >= 25.f) { vsum = var; vcnt = 1.f; }
  }
  __shared__ float red[2];
  if (t < 2) red[t] = 0.f;
  __syncthreads();
  vsum = wave_sum(vsum); vcnt = wave_sum(vcnt);
  if ((t & 63) == 0) { atomicAdd(&red[0], vsum); atomicAdd(&red[1], vcnt); }
  __syncthreads();
  if (t == 0) {
    float l_distill = acc[1] * (1.f / NPIX);
    float bcnt = acc[3];
    float l_bpl = (bcnt > 0.f) ? acc[2] / fmaxf(bcnt, 1.f) : 0.f;
    float l_align = acc[5] * (1.f / (BN*HH*(WW-1))) + acc[6] * (1.f / (BN*(HH-1)*WW));
    float l_ent = acc[4] * (1.f / NPIX);
    float l_ib = 0.5f * (acc[7] * (1.f / (BN*(HH-1)*WW)) + acc[8] * (1.f / (BN*HH*(WW-1))));
    float l_proto = -acc[9] * (1.f / NPIX);
    float l_iu = red[0] / fmaxf(red[1], 1.f);
    out[0] = 1.0f*l_distill + 0.5f*l_bpl + 5.0f*l_align + 0.5f*l_proto +
             0.3f*l_ent + 0.5f*l_iu + 0.5f*l_ib;
  }
}

extern "C" void kernel_launch(void* const* d_in, const int* in_sizes, int n_in,
                              void* d_out, int out_size, void* d_ws, size_t ws_size,
                              hipStream_t stream) {
  (void)in_sizes; (void)n_in; (void)out_size; (void)ws_size;
  const float* logits = (const float*)d_in[0];
  const float* cause  = (const float*)d_in[1];
  const float* feats  = (const float*)d_in[2];
  const float* depth  = (const float*)d_in[3];
  const int*   inst   = (const int*)d_in[4];
  float* ws = (float*)d_ws;
  float* acc = ws + OFF_ACC;
  float* s1  = ws + OFF_S1;
  float* s2  = ws + OFF_S2;
  float* cnt = ws + OFF_CNT;
  float* nsq8 = ws + OFF_NSQ8;
  float* ce  = ws + OFF_CE;
  float* Pp  = ws + OFF_PP;
  float* Qp  = ws + OFF_QP;
  unsigned char* lab = (unsigned char*)(ws + OFF_LAB);
  unsigned short* probs = (unsigned short*)(ws + OFF_PROBS);
  unsigned char* fbf = (unsigned char*)(ws + OFF_FBF);
  unsigned char* wbf = (unsigned char*)(ws + OFF_WBF);
  float* out = (float*)d_out;

  k_zero<<<(ZERO_N + 255) / 256, 256, 0, stream>>>(ws, ZERO_N);
  k_big<<<800, 256, 0, stream>>>(feats, logits, cause, depth, fbf, nsq8, lab, ce,
                                 probs, wbf, acc);
  k_mainB<<<400, 256, 0, stream>>>(nsq8, wbf);
  k_gemmtail<<<GEMMB + TAILB, 256, 0, stream>>>(fbf, wbf, Pp, Qp, probs, depth, inst,
                                                lab, ce, acc, s1, s2, cnt);
  k_pfinal<<<BN * CC, 256, 0, stream>>>(Pp, Qp, acc);
  k_final<<<1, 256, 0, stream>>>(s1, s2, cnt, acc, out);
}